// Round 2
// baseline (351.843 us; speedup 1.0000x reference)
//
#include <hip/hip_runtime.h>

#define H        400
#define W_CROP   400
#define PSF_W    121
#define MARGIN   44
#define IM       488
#define NZ       64
#define N_EMIT   2048
#define PSF_AREA (PSF_W * PSF_W)     /* 14641 */
#define SIGMA2   100.0f              /* SIGMA_READ^2 */
#define TILE     16
#define TB       25                  /* tiles per side: 400/16 */
#define NTILES   (TB * TB)           /* 625 */
#define CAP      640                 /* max emitters per tile bin */

static __device__ __forceinline__ unsigned enc_ord(float f) {
    unsigned u = __float_as_uint(f);
    return (u & 0x80000000u) ? ~u : (u | 0x80000000u);
}
static __device__ __forceinline__ float dec_ord(unsigned u) {
    return __uint_as_float((u & 0x80000000u) ? (u & 0x7fffffffu) : ~u);
}

/* zero bin counts + init min/max */
__global__ void zero_kernel(int* __restrict__ counts, unsigned* __restrict__ minmax) {
    int i = blockIdx.x * 256 + threadIdx.x;
    if (i < NTILES) counts[i] = 0;
    if (i == 0) { minmax[0] = 0xFFFFFFFFu; minmax[1] = 0u; }
}

/* per-z-slice PSF sums: S, last-row sum, last-col sum, corner */
__global__ __launch_bounds__(256) void zsum_kernel(const float* __restrict__ psf_bank,
                                                   float* __restrict__ zmeta) {
    __shared__ float red[4][4];
    const int zi = blockIdx.x;
    const float* __restrict__ p = psf_bank + (size_t)zi * PSF_AREA;
    float S = 0.f, R = 0.f, C = 0.f, K = 0.f;
    for (int i = threadIdx.x; i < PSF_AREA; i += 256) {
        const float v = p[i];
        const int r = i / PSF_W;
        const int c = i - r * PSF_W;
        S += v;
        if (r == PSF_W - 1) R += v;
        if (c == PSF_W - 1) C += v;
        if (r == PSF_W - 1 && c == PSF_W - 1) K += v;
    }
    #pragma unroll
    for (int off = 32; off > 0; off >>= 1) {
        S += __shfl_down(S, off, 64);
        R += __shfl_down(R, off, 64);
        C += __shfl_down(C, off, 64);
        K += __shfl_down(K, off, 64);
    }
    const int wave = threadIdx.x >> 6, lane = threadIdx.x & 63;
    if (lane == 0) { red[wave][0] = S; red[wave][1] = R; red[wave][2] = C; red[wave][3] = K; }
    __syncthreads();
    if (threadIdx.x == 0) {
        float4 o;
        o.x = red[0][0] + red[1][0] + red[2][0] + red[3][0];
        o.y = red[0][1] + red[1][1] + red[2][1] + red[3][1];
        o.z = red[0][2] + red[1][2] + red[2][2] + red[3][2];
        o.w = red[0][3] + red[1][3] + red[2][3] + red[3][3];
        *(float4*)(zmeta + 4 * zi) = o;
    }
}

/* per-emitter meta (scale-folded bilinear weights) + tile binning */
__global__ __launch_bounds__(256) void emeta_bin_kernel(
        const float* __restrict__ xyz, const float* __restrict__ nph_arr,
        const float* __restrict__ zmeta, float* __restrict__ emeta,
        int* __restrict__ counts, unsigned short* __restrict__ bins)
{
    const int e = blockIdx.x * 256 + threadIdx.x;
    if (e >= N_EMIT) return;
    const float x = xyz[3 * e + 0];
    const float y = xyz[3 * e + 1];
    const float z = xyz[3 * e + 2];
    const float nph = nph_arr[e];

    int zi = (int)rintf((z + 2.0f) / 4.0f * 63.0f);
    zi = min(max(zi, 0), NZ - 1);

    const float lx = (x * 100.0f) / 11.0f;
    const float ly = (y * 100.0f) / 11.0f;
    const float r0f = (ly + 244.0f) - 60.5f;
    const float c0f = (lx + 244.0f) - 60.5f;
    const int   r0 = (int)floorf(r0f);
    const int   c0 = (int)floorf(c0f);
    const float rs = r0f - floorf(r0f);
    const float cs = c0f - floorf(c0f);

    const float4 zm = *(const float4*)(zmeta + 4 * zi);
    const float ssum = zm.x - rs * zm.y - cs * zm.z + rs * cs * zm.w;
    const float scale = nph / ssum;

    const float w00 = (1.0f - rs) * (1.0f - cs);
    const float w01 = (1.0f - rs) * cs;
    const float w10 = rs * (1.0f - cs);
    const float w11 = rs * cs;

    float4 m0, m1;
    m0.x = (float)r0; m0.y = (float)c0; m0.z = scale * w00; m0.w = scale * w01;
    m1.x = scale * w10; m1.y = scale * w11; m1.z = __int_as_float(zi * PSF_AREA); m1.w = 0.f;
    *(float4*)(emeta + 8 * e)     = m0;
    *(float4*)(emeta + 8 * e + 4) = m1;

    /* tiles (crop coords) whose canvas rows [44+16t, 59+16t] intersect [r0, r0+120] */
    const int trlo = max(0, (r0 - MARGIN) >> 4);          /* ceil((r0-59)/16) */
    const int trhi = min(TB - 1, (r0 + 76) >> 4);
    const int tclo = max(0, (c0 - MARGIN) >> 4);
    const int tchi = min(TB - 1, (c0 + 76) >> 4);
    for (int tr = trlo; tr <= trhi; ++tr)
        for (int tc = tclo; tc <= tchi; ++tc) {
            const int t = tr * TB + tc;
            const int idx = atomicAdd(&counts[t], 1);
            if (idx < CAP) bins[(size_t)t * CAP + idx] = (unsigned short)e;
        }
}

/* one block per 16x16 output tile; gather all binned emitters, add noise,
   write unnormalized image to out, block-reduce min/max */
__global__ __launch_bounds__(256) void gather_kernel(
        const float* __restrict__ psf_bank, const float* __restrict__ emeta,
        const int* __restrict__ counts, const unsigned short* __restrict__ bins,
        const float* __restrict__ noise, float* __restrict__ vout,
        unsigned* __restrict__ minmax)
{
    const int tile = blockIdx.x;
    const int tr = tile / TB, tc = tile - tr * TB;
    const int py = threadIdx.x >> 4, px = threadIdx.x & 15;
    const int orow = tr * TILE + py, ocol = tc * TILE + px;
    const int crow = orow + MARGIN,  ccol = ocol + MARGIN;

    int n = counts[tile];
    n = min(n, CAP);
    const unsigned short* __restrict__ bin = bins + (size_t)tile * CAP;

    float acc = 0.f;
    for (int k = 0; k < n; ++k) {
        const int e = __builtin_amdgcn_readfirstlane((int)bin[k]);
        const float4 m0 = *(const float4*)(emeta + 8 * e);
        const float4 m1 = *(const float4*)(emeta + 8 * e + 4);
        const int pr = crow - (int)m0.x;
        const int pc = ccol - (int)m0.y;
        if ((unsigned)pr <= 120u && (unsigned)pc <= 120u) {
            const float* __restrict__ p = psf_bank + __float_as_int(m1.z) + pr * PSF_W + pc;
            float v = m0.z * p[0];
            if (pc > 0)           v = fmaf(m0.w, p[-1], v);
            if (pr > 0)           v = fmaf(m1.x, p[-PSF_W], v);
            if (pr > 0 && pc > 0) v = fmaf(m1.y, p[-PSF_W - 1], v);
            acc += v;
        }
    }

    const float nz = noise[orow * W_CROP + ocol];
    const float v = acc + sqrtf(fmaxf(acc, 0.0f) + SIGMA2) * nz;
    vout[orow * W_CROP + ocol] = v;

    float vmin = v, vmax = v;
    #pragma unroll
    for (int off = 32; off > 0; off >>= 1) {
        vmin = fminf(vmin, __shfl_down(vmin, off, 64));
        vmax = fmaxf(vmax, __shfl_down(vmax, off, 64));
    }
    if ((threadIdx.x & 63) == 0) {
        atomicMin(&minmax[0], enc_ord(vmin));
        atomicMax(&minmax[1], enc_ord(vmax));
    }
}

/* in-place normalize of out */
__global__ __launch_bounds__(256) void finalize_kernel(float* __restrict__ vout,
                                                       const unsigned* __restrict__ minmax)
{
    const int i = blockIdx.x * 256 + threadIdx.x;
    const float mn = dec_ord(minmax[0]);
    const float mx = dec_ord(minmax[1]);
    vout[i] = (vout[i] - mn) / (mx - mn);
}

extern "C" void kernel_launch(void* const* d_in, const int* in_sizes, int n_in,
                              void* d_out, int out_size, void* d_ws, size_t ws_size,
                              hipStream_t stream) {
    const float* xyz      = (const float*)d_in[0];  /* (1,2048,3) */
    const float* nph      = (const float*)d_in[1];  /* (1,2048)   */
    /* d_in[2] = xy_center, unused by reference */
    const float* psf_bank = (const float*)d_in[3];  /* (64,121,121) */
    const float* noise    = (const float*)d_in[4];  /* (400,400) */
    float* out = (float*)d_out;

    /* ws layout (bytes):
       zmeta : 0       .. 1024        (64 * float4)
       emeta : 1024    .. 66560       (2048 * 8 floats)
       counts: 66560   .. 69120       (625 ints, padded)
       bins  : 69120   .. 869120      (625 * 640 * u16)
       minmax: 869120  .. 869128                                  */
    char* ws = (char*)d_ws;
    float*          zmeta  = (float*)(ws + 0);
    float*          emeta  = (float*)(ws + 1024);
    int*            counts = (int*)(ws + 66560);
    unsigned short* bins   = (unsigned short*)(ws + 69120);
    unsigned*       minmax = (unsigned*)(ws + 869120);

    const int npix = H * W_CROP;  /* 160000 = 625 * 256 */

    zero_kernel<<<3, 256, 0, stream>>>(counts, minmax);
    zsum_kernel<<<NZ, 256, 0, stream>>>(psf_bank, zmeta);
    emeta_bin_kernel<<<(N_EMIT + 255) / 256, 256, 0, stream>>>(xyz, nph, zmeta, emeta, counts, bins);
    gather_kernel<<<NTILES, 256, 0, stream>>>(psf_bank, emeta, counts, bins, noise, out, minmax);
    finalize_kernel<<<npix / 256, 256, 0, stream>>>(out, minmax);
}

// Round 3
// 203.036 us; speedup vs baseline: 1.7329x; 1.7329x over previous
//
#include <hip/hip_runtime.h>

#define H        400
#define W_CROP   400
#define PSF_W    121
#define MARGIN   44
#define IM       488
#define NZ       64
#define N_EMIT   2048
#define PSF_AREA (PSF_W * PSF_W)     /* 14641 */
#define SIGMA2   100.0f              /* SIGMA_READ^2 */
#define TILE     16
#define TB       25                  /* tiles per side: 400/16 */
#define NTILES   (TB * TB)           /* 625 */
#define CAP      640                 /* max emitters per tile bin */
#define SPLIT    8                   /* chunks per tile */
#define MAXCHUNK (CAP / SPLIT)       /* 80 */
#define NPIX     (H * W_CROP)        /* 160000 */

static __device__ __forceinline__ unsigned enc_ord(float f) {
    unsigned u = __float_as_uint(f);
    return (u & 0x80000000u) ? ~u : (u | 0x80000000u);
}
static __device__ __forceinline__ float dec_ord(unsigned u) {
    return __uint_as_float((u & 0x80000000u) ? (u & 0x7fffffffu) : ~u);
}

/* 64 blocks: per-z PSF sums (S, last-row, last-col, corner) + zero out/counts + init minmax */
__global__ __launch_bounds__(256) void init_zsum_kernel(
        const float* __restrict__ psf_bank, float* __restrict__ zmeta,
        int* __restrict__ counts, unsigned* __restrict__ minmax,
        float* __restrict__ out)
{
    __shared__ float red[4][4];
    const int zi = blockIdx.x;
    const int gtid = zi * 256 + threadIdx.x;

    for (int i = gtid; i < NPIX; i += 64 * 256) out[i] = 0.0f;
    if (gtid < NTILES) counts[gtid] = 0;
    if (gtid == 0) { minmax[0] = 0xFFFFFFFFu; minmax[1] = 0u; }

    const float* __restrict__ p = psf_bank + (size_t)zi * PSF_AREA;
    float S = 0.f, R = 0.f, C = 0.f, K = 0.f;
    for (int i = threadIdx.x; i < PSF_AREA; i += 256) {
        const float v = p[i];
        const int r = i / PSF_W;
        const int c = i - r * PSF_W;
        S += v;
        if (r == PSF_W - 1) R += v;
        if (c == PSF_W - 1) C += v;
        if (r == PSF_W - 1 && c == PSF_W - 1) K += v;
    }
    #pragma unroll
    for (int off = 32; off > 0; off >>= 1) {
        S += __shfl_down(S, off, 64);
        R += __shfl_down(R, off, 64);
        C += __shfl_down(C, off, 64);
        K += __shfl_down(K, off, 64);
    }
    const int wave = threadIdx.x >> 6, lane = threadIdx.x & 63;
    if (lane == 0) { red[wave][0] = S; red[wave][1] = R; red[wave][2] = C; red[wave][3] = K; }
    __syncthreads();
    if (threadIdx.x == 0) {
        float4 o;
        o.x = red[0][0] + red[1][0] + red[2][0] + red[3][0];
        o.y = red[0][1] + red[1][1] + red[2][1] + red[3][1];
        o.z = red[0][2] + red[1][2] + red[2][2] + red[3][2];
        o.w = red[0][3] + red[1][3] + red[2][3] + red[3][3];
        *(float4*)(zmeta + 4 * zi) = o;
    }
}

/* per-emitter meta (scale-folded bilinear weights) + tile binning */
__global__ __launch_bounds__(256) void emeta_bin_kernel(
        const float* __restrict__ xyz, const float* __restrict__ nph_arr,
        const float* __restrict__ zmeta, float* __restrict__ emeta,
        int* __restrict__ counts, unsigned short* __restrict__ bins)
{
    const int e = blockIdx.x * 256 + threadIdx.x;
    if (e >= N_EMIT) return;
    const float x = xyz[3 * e + 0];
    const float y = xyz[3 * e + 1];
    const float z = xyz[3 * e + 2];
    const float nph = nph_arr[e];

    int zi = (int)rintf((z + 2.0f) / 4.0f * 63.0f);
    zi = min(max(zi, 0), NZ - 1);

    const float lx = (x * 100.0f) / 11.0f;
    const float ly = (y * 100.0f) / 11.0f;
    const float r0f = (ly + 244.0f) - 60.5f;
    const float c0f = (lx + 244.0f) - 60.5f;
    const int   r0 = (int)floorf(r0f);
    const int   c0 = (int)floorf(c0f);
    const float rs = r0f - floorf(r0f);
    const float cs = c0f - floorf(c0f);

    const float4 zm = *(const float4*)(zmeta + 4 * zi);
    const float ssum = zm.x - rs * zm.y - cs * zm.z + rs * cs * zm.w;
    const float scale = nph / ssum;

    const float w00 = (1.0f - rs) * (1.0f - cs);
    const float w01 = (1.0f - rs) * cs;
    const float w10 = rs * (1.0f - cs);
    const float w11 = rs * cs;

    float4 m0, m1;
    m0.x = (float)r0; m0.y = (float)c0; m0.z = scale * w00; m0.w = scale * w01;
    m1.x = scale * w10; m1.y = scale * w11; m1.z = __int_as_float(zi * PSF_AREA); m1.w = 0.f;
    *(float4*)(emeta + 8 * e)     = m0;
    *(float4*)(emeta + 8 * e + 4) = m1;

    const int trlo = max(0, (r0 - MARGIN) >> 4);
    const int trhi = min(TB - 1, (r0 + 76) >> 4);
    const int tclo = max(0, (c0 - MARGIN) >> 4);
    const int tchi = min(TB - 1, (c0 + 76) >> 4);
    for (int tr = trlo; tr <= trhi; ++tr)
        for (int tc = tclo; tc <= tchi; ++tc) {
            const int t = tr * TB + tc;
            const int idx = atomicAdd(&counts[t], 1);
            if (idx < CAP) bins[(size_t)t * CAP + idx] = (unsigned short)e;
        }
}

/* grid = NTILES*SPLIT blocks; each block handles one (tile, emitter-chunk).
   Meta staged in LDS; per-pixel partial accumulated, then one atomicAdd to out. */
__global__ __launch_bounds__(256) void gather_kernel(
        const float* __restrict__ psf_bank, const float* __restrict__ emeta,
        const int* __restrict__ counts, const unsigned short* __restrict__ bins,
        float* __restrict__ out)
{
    __shared__ float4 smeta[2 * MAXCHUNK];

    const int tile  = blockIdx.x / SPLIT;
    const int chunk = blockIdx.x - tile * SPLIT;
    const int tr = tile / TB, tc = tile - tr * TB;
    const int py = threadIdx.x >> 4, px = threadIdx.x & 15;
    const int orow = tr * TILE + py, ocol = tc * TILE + px;
    const int crow = orow + MARGIN,  ccol = ocol + MARGIN;

    const int n = min(counts[tile], CAP);
    const int nmine = (chunk < n) ? ((n - chunk + SPLIT - 1) / SPLIT) : 0;
    const unsigned short* __restrict__ bin = bins + (size_t)tile * CAP;

    for (int j = threadIdx.x; j < nmine * 8; j += 256) {
        const int jj = j >> 3, w = j & 7;
        const int e = (int)bin[chunk + jj * SPLIT];
        ((float*)smeta)[jj * 8 + w] = emeta[8 * e + w];
    }
    __syncthreads();

    float acc0 = 0.f, acc1 = 0.f;
    auto body = [&](int j, float& acc) {
        const float4 m0 = smeta[2 * j];
        const float4 m1 = smeta[2 * j + 1];
        const int pr = crow - (int)m0.x;
        const int pc = ccol - (int)m0.y;
        if ((unsigned)pr <= 120u && (unsigned)pc <= 120u) {
            const float* __restrict__ p = psf_bank + __float_as_int(m1.z) + pr * PSF_W + pc;
            float v = m0.z * p[0];
            if (pc > 0)           v = fmaf(m0.w, p[-1], v);
            if (pr > 0)           v = fmaf(m1.x, p[-PSF_W], v);
            if (pr > 0 && pc > 0) v = fmaf(m1.y, p[-PSF_W - 1], v);
            acc += v;
        }
    };
    int j = 0;
    for (; j + 2 <= nmine; j += 2) { body(j, acc0); body(j + 1, acc1); }
    for (; j < nmine; ++j) body(j, acc0);

    const float acc = acc0 + acc1;
    if (acc != 0.f) atomicAdd(&out[orow * W_CROP + ocol], acc);
}

/* read accumulated image from out, apply noise, write back, reduce min/max */
__global__ __launch_bounds__(256) void noise_minmax_kernel(
        float* __restrict__ out, const float* __restrict__ noise,
        unsigned* __restrict__ minmax)
{
    const int i = blockIdx.x * 256 + threadIdx.x;
    const float im = out[i];
    const float v = im + sqrtf(fmaxf(im, 0.0f) + SIGMA2) * noise[i];
    out[i] = v;

    float vmin = v, vmax = v;
    #pragma unroll
    for (int off = 32; off > 0; off >>= 1) {
        vmin = fminf(vmin, __shfl_down(vmin, off, 64));
        vmax = fmaxf(vmax, __shfl_down(vmax, off, 64));
    }
    if ((threadIdx.x & 63) == 0) {
        atomicMin(&minmax[0], enc_ord(vmin));
        atomicMax(&minmax[1], enc_ord(vmax));
    }
}

__global__ __launch_bounds__(256) void finalize_kernel(float* __restrict__ out,
                                                       const unsigned* __restrict__ minmax)
{
    const int i = blockIdx.x * 256 + threadIdx.x;
    const float mn = dec_ord(minmax[0]);
    const float mx = dec_ord(minmax[1]);
    out[i] = (out[i] - mn) / (mx - mn);
}

extern "C" void kernel_launch(void* const* d_in, const int* in_sizes, int n_in,
                              void* d_out, int out_size, void* d_ws, size_t ws_size,
                              hipStream_t stream) {
    const float* xyz      = (const float*)d_in[0];  /* (1,2048,3) */
    const float* nph      = (const float*)d_in[1];  /* (1,2048)   */
    /* d_in[2] = xy_center, unused by reference */
    const float* psf_bank = (const float*)d_in[3];  /* (64,121,121) */
    const float* noise    = (const float*)d_in[4];  /* (400,400) */
    float* out = (float*)d_out;

    /* ws layout (bytes):
       zmeta : 0       .. 1024        (64 * float4)
       emeta : 1024    .. 66560       (2048 * 8 floats)
       counts: 66560   .. 69120       (625 ints, padded)
       bins  : 69120   .. 869120      (625 * 640 * u16)
       minmax: 869120  .. 869128                                  */
    char* ws = (char*)d_ws;
    float*          zmeta  = (float*)(ws + 0);
    float*          emeta  = (float*)(ws + 1024);
    int*            counts = (int*)(ws + 66560);
    unsigned short* bins   = (unsigned short*)(ws + 69120);
    unsigned*       minmax = (unsigned*)(ws + 869120);

    init_zsum_kernel<<<NZ, 256, 0, stream>>>(psf_bank, zmeta, counts, minmax, out);
    emeta_bin_kernel<<<(N_EMIT + 255) / 256, 256, 0, stream>>>(xyz, nph, zmeta, emeta, counts, bins);
    gather_kernel<<<NTILES * SPLIT, 256, 0, stream>>>(psf_bank, emeta, counts, bins, out);
    noise_minmax_kernel<<<NPIX / 256, 256, 0, stream>>>(out, noise, minmax);
    finalize_kernel<<<NPIX / 256, 256, 0, stream>>>(out, minmax);
}

// Round 4
// 84.972 us; speedup vs baseline: 4.1407x; 2.3894x over previous
//
#include <hip/hip_runtime.h>

#define H        400
#define W_CROP   400
#define PSF_W    121
#define MARGIN   44
#define IM       488
#define NZ       64
#define N_EMIT   2048
#define PSF_AREA (PSF_W * PSF_W)     /* 14641 */
#define SIGMA2   100.0f              /* SIGMA_READ^2 */
#define TILE     16
#define TB       25                  /* tiles per side: 400/16 */
#define NTILES   (TB * TB)           /* 625 */
#define CAP      640                 /* max emitters per tile bin */
#define SPLIT    8                   /* chunks per tile */
#define MAXCHUNK (CAP / SPLIT)       /* 80 */
#define NPIX     (H * W_CROP)        /* 160000 */
#define WIN      9                   /* max tiles per dim an emitter touches */

static __device__ __forceinline__ unsigned enc_ord(float f) {
    unsigned u = __float_as_uint(f);
    return (u & 0x80000000u) ? ~u : (u | 0x80000000u);
}
static __device__ __forceinline__ float dec_ord(unsigned u) {
    return __uint_as_float((u & 0x80000000u) ? (u & 0x7fffffffu) : ~u);
}

/* 64 blocks x 1024 thr: per-z PSF sums + zero out/counts + init minmax */
__global__ __launch_bounds__(1024) void init_zsum_kernel(
        const float* __restrict__ psf_bank, float* __restrict__ zmeta,
        int* __restrict__ counts, unsigned* __restrict__ minmax,
        float* __restrict__ out)
{
    __shared__ float red[16][4];
    const int zi = blockIdx.x;
    const int gtid = zi * 1024 + threadIdx.x;

    for (int i = gtid; i < NPIX; i += 64 * 1024) out[i] = 0.0f;
    if (gtid < NTILES) counts[gtid] = 0;
    if (gtid == 0) { minmax[0] = 0xFFFFFFFFu; minmax[1] = 0u; }

    const float* __restrict__ p = psf_bank + (size_t)zi * PSF_AREA;
    float S = 0.f, R = 0.f, C = 0.f, K = 0.f;
    for (int i = threadIdx.x; i < PSF_AREA; i += 1024) {
        const float v = p[i];
        const int r = i / PSF_W;
        const int c = i - r * PSF_W;
        S += v;
        if (r == PSF_W - 1) R += v;
        if (c == PSF_W - 1) C += v;
        if (r == PSF_W - 1 && c == PSF_W - 1) K += v;
    }
    #pragma unroll
    for (int off = 32; off > 0; off >>= 1) {
        S += __shfl_down(S, off, 64);
        R += __shfl_down(R, off, 64);
        C += __shfl_down(C, off, 64);
        K += __shfl_down(K, off, 64);
    }
    const int wave = threadIdx.x >> 6, lane = threadIdx.x & 63;
    if (lane == 0) { red[wave][0] = S; red[wave][1] = R; red[wave][2] = C; red[wave][3] = K; }
    __syncthreads();
    if (threadIdx.x == 0) {
        float4 o = make_float4(0.f, 0.f, 0.f, 0.f);
        #pragma unroll
        for (int wv = 0; wv < 16; ++wv) {
            o.x += red[wv][0]; o.y += red[wv][1]; o.z += red[wv][2]; o.w += red[wv][3];
        }
        *(float4*)(zmeta + 4 * zi) = o;
    }
}

/* one thread per (emitter, window-slot); w==0 thread also writes emitter meta.
   grid = 2048*81/256 = 648 blocks exactly. */
__global__ __launch_bounds__(256) void emeta_bin_kernel(
        const float* __restrict__ xyz, const float* __restrict__ nph_arr,
        const float* __restrict__ zmeta, float* __restrict__ emeta,
        int* __restrict__ counts, unsigned short* __restrict__ bins)
{
    const int gid = blockIdx.x * 256 + threadIdx.x;
    const int e = gid / (WIN * WIN);
    const int w = gid - e * (WIN * WIN);

    const float x = xyz[3 * e + 0];
    const float y = xyz[3 * e + 1];
    const float lx = (x * 100.0f) / 11.0f;
    const float ly = (y * 100.0f) / 11.0f;
    const float r0f = (ly + 244.0f) - 60.5f;
    const float c0f = (lx + 244.0f) - 60.5f;
    const int   r0 = (int)floorf(r0f);
    const int   c0 = (int)floorf(c0f);

    const int trlo = max(0, (r0 - MARGIN) >> 4);
    const int trhi = min(TB - 1, (r0 + 76) >> 4);
    const int tclo = max(0, (c0 - MARGIN) >> 4);
    const int tchi = min(TB - 1, (c0 + 76) >> 4);

    const int tr = trlo + w / WIN;
    const int tc = tclo + (w - (w / WIN) * WIN);
    if (tr <= trhi && tc <= tchi) {
        const int t = tr * TB + tc;
        const int idx = atomicAdd(&counts[t], 1);
        if (idx < CAP) bins[(size_t)t * CAP + idx] = (unsigned short)e;
    }

    if (w == 0) {
        const float z = xyz[3 * e + 2];
        const float nph = nph_arr[e];
        int zi = (int)rintf((z + 2.0f) / 4.0f * 63.0f);
        zi = min(max(zi, 0), NZ - 1);
        const float rs = r0f - floorf(r0f);
        const float cs = c0f - floorf(c0f);
        const float4 zm = *(const float4*)(zmeta + 4 * zi);
        const float ssum = zm.x - rs * zm.y - cs * zm.z + rs * cs * zm.w;
        const float scale = nph / ssum;
        float4 m0, m1;
        m0.x = (float)r0; m0.y = (float)c0;
        m0.z = scale * (1.0f - rs) * (1.0f - cs);   /* w00 */
        m0.w = scale * (1.0f - rs) * cs;            /* w01 */
        m1.x = scale * rs * (1.0f - cs);            /* w10 */
        m1.y = scale * rs * cs;                     /* w11 */
        m1.z = __int_as_float(zi * PSF_AREA); m1.w = 0.f;
        *(float4*)(emeta + 8 * e)     = m0;
        *(float4*)(emeta + 8 * e + 4) = m1;
    }
}

/* grid = NTILES*SPLIT single-wave blocks; thread = (col, 4-row vertical strip).
   Per emitter: 10 clamped loads (5 rows x 2 cols) feed 4 bilinear pixels. */
__global__ __launch_bounds__(64) void gather_kernel(
        const float* __restrict__ psf_bank, const float* __restrict__ emeta,
        const int* __restrict__ counts, const unsigned short* __restrict__ bins,
        float* __restrict__ out)
{
    __shared__ float4 smeta[2 * MAXCHUNK];

    const int tile  = blockIdx.x >> 3;            /* SPLIT = 8 */
    const int chunk = blockIdx.x & (SPLIT - 1);
    const int tr = tile / TB, tc = tile - tr * TB;
    const int px = threadIdx.x & 15;              /* col within tile */
    const int wy = threadIdx.x >> 4;              /* 0..3: 4-row strip */
    const int orow0 = tr * TILE + wy * 4;
    const int ocol  = tc * TILE + px;
    const int crow0 = orow0 + MARGIN;
    const int ccol  = ocol + MARGIN;

    const int n = min(counts[tile], CAP);
    const int nmine = (chunk < n) ? ((n - chunk + SPLIT - 1) / SPLIT) : 0;
    const unsigned short* __restrict__ bin = bins + (size_t)tile * CAP;

    for (int j = threadIdx.x; j < nmine * 8; j += 64) {
        const int jj = j >> 3, ww = j & 7;
        const int e = (int)bin[chunk + jj * SPLIT];
        ((float*)smeta)[jj * 8 + ww] = emeta[8 * e + ww];
    }
    __syncthreads();

    float acc0[4] = {0.f, 0.f, 0.f, 0.f};
    float acc1[4] = {0.f, 0.f, 0.f, 0.f};

    auto body = [&](int j, float* acc) {
        const float4 m0 = smeta[2 * j];
        const float4 m1 = smeta[2 * j + 1];
        const int pr0 = crow0 - (int)m0.x;        /* row offset of strip pixel 0 */
        const int pc  = ccol  - (int)m0.y;
        const bool pcok = (unsigned)pc <= 120u;
        const int pcl = min(max(pc, 0), 120);
        const int pcm = max(pc - 1, 0);
        const float* __restrict__ p = psf_bank + __float_as_int(m1.z);
        float a[5], b[5];
        #pragma unroll
        for (int i = 0; i < 5; ++i) {
            const int row = pr0 - 1 + i;
            const bool rok = (unsigned)row <= 120u;
            const int rowc = min(max(row, 0), 120);
            const float* __restrict__ q = p + rowc * PSF_W;
            const float av = q[pcl];
            const float bv = q[pcm];
            a[i] = rok ? av : 0.f;
            b[i] = (rok && pc > 0) ? bv : 0.f;
        }
        #pragma unroll
        for (int k = 0; k < 4; ++k) {
            float v = m0.z * a[k + 1];
            v = fmaf(m1.x, a[k],     v);
            v = fmaf(m0.w, b[k + 1], v);
            v = fmaf(m1.y, b[k],     v);
            const bool ok = pcok && ((unsigned)(pr0 + k) <= 120u);
            acc[k] += ok ? v : 0.f;
        }
    };

    int j = 0;
    for (; j + 2 <= nmine; j += 2) { body(j, acc0); body(j + 1, acc1); }
    for (; j < nmine; ++j) body(j, acc0);

    #pragma unroll
    for (int k = 0; k < 4; ++k) {
        const float acc = acc0[k] + acc1[k];
        if (acc != 0.f) atomicAdd(&out[(orow0 + k) * W_CROP + ocol], acc);
    }
}

/* float4: read accumulated image, apply noise, write back, reduce min/max */
__global__ __launch_bounds__(256) void noise_minmax_kernel(
        float* __restrict__ out, const float* __restrict__ noise,
        unsigned* __restrict__ minmax)
{
    const int i = blockIdx.x * 256 + threadIdx.x;
    float vmin = 1e30f, vmax = -1e30f;
    if (i < NPIX / 4) {
        float4 im = ((float4*)out)[i];
        const float4 nz = ((const float4*)noise)[i];
        im.x += sqrtf(fmaxf(im.x, 0.f) + SIGMA2) * nz.x;
        im.y += sqrtf(fmaxf(im.y, 0.f) + SIGMA2) * nz.y;
        im.z += sqrtf(fmaxf(im.z, 0.f) + SIGMA2) * nz.z;
        im.w += sqrtf(fmaxf(im.w, 0.f) + SIGMA2) * nz.w;
        ((float4*)out)[i] = im;
        vmin = fminf(fminf(im.x, im.y), fminf(im.z, im.w));
        vmax = fmaxf(fmaxf(im.x, im.y), fmaxf(im.z, im.w));
    }
    #pragma unroll
    for (int off = 32; off > 0; off >>= 1) {
        vmin = fminf(vmin, __shfl_down(vmin, off, 64));
        vmax = fmaxf(vmax, __shfl_down(vmax, off, 64));
    }
    if ((threadIdx.x & 63) == 0) {
        atomicMin(&minmax[0], enc_ord(vmin));
        atomicMax(&minmax[1], enc_ord(vmax));
    }
}

__global__ __launch_bounds__(256) void finalize_kernel(float* __restrict__ out,
                                                       const unsigned* __restrict__ minmax)
{
    const int i = blockIdx.x * 256 + threadIdx.x;
    if (i >= NPIX / 4) return;
    const float mn = dec_ord(minmax[0]);
    const float inv = 1.0f / (dec_ord(minmax[1]) - mn);
    float4 v = ((float4*)out)[i];
    v.x = (v.x - mn) * inv;
    v.y = (v.y - mn) * inv;
    v.z = (v.z - mn) * inv;
    v.w = (v.w - mn) * inv;
    ((float4*)out)[i] = v;
}

extern "C" void kernel_launch(void* const* d_in, const int* in_sizes, int n_in,
                              void* d_out, int out_size, void* d_ws, size_t ws_size,
                              hipStream_t stream) {
    const float* xyz      = (const float*)d_in[0];  /* (1,2048,3) */
    const float* nph      = (const float*)d_in[1];  /* (1,2048)   */
    /* d_in[2] = xy_center, unused by reference */
    const float* psf_bank = (const float*)d_in[3];  /* (64,121,121) */
    const float* noise    = (const float*)d_in[4];  /* (400,400) */
    float* out = (float*)d_out;

    /* ws layout (bytes):
       zmeta : 0       .. 1024        (64 * float4)
       emeta : 1024    .. 66560       (2048 * 8 floats)
       counts: 66560   .. 69120       (625 ints, padded)
       bins  : 69120   .. 869120      (625 * 640 * u16)
       minmax: 869120  .. 869128                                  */
    char* ws = (char*)d_ws;
    float*          zmeta  = (float*)(ws + 0);
    float*          emeta  = (float*)(ws + 1024);
    int*            counts = (int*)(ws + 66560);
    unsigned short* bins   = (unsigned short*)(ws + 69120);
    unsigned*       minmax = (unsigned*)(ws + 869120);

    init_zsum_kernel<<<NZ, 1024, 0, stream>>>(psf_bank, zmeta, counts, minmax, out);
    emeta_bin_kernel<<<(N_EMIT * WIN * WIN) / 256, 256, 0, stream>>>(xyz, nph, zmeta, emeta, counts, bins);
    gather_kernel<<<NTILES * SPLIT, 64, 0, stream>>>(psf_bank, emeta, counts, bins, out);
    noise_minmax_kernel<<<(NPIX / 4 + 255) / 256, 256, 0, stream>>>(out, noise, minmax);
    finalize_kernel<<<(NPIX / 4 + 255) / 256, 256, 0, stream>>>(out, minmax);
}